// Round 9
// baseline (4111.370 us; speedup 1.0000x reference)
//
#include <hip/hip_runtime.h>
#include <hip/hip_bf16.h>

#define SORB  64
#define HID   512
#define BATCH 4096
#define N3H   1536   // 3*HID
#define KD    512
#define PI_F  3.14159265358979f

typedef _Float16 half8 __attribute__((ext_vector_type(8)));
typedef float    floatx4 __attribute__((ext_vector_type(4)));

__device__ __forceinline__ float sigmoidf_(float x) { return 1.f / (1.f + __expf(-x)); }
__device__ __forceinline__ float tanhf_(float x) {
    x = fminf(fmaxf(x, -15.f), 15.f);
    const float e2 = __expf(2.f * x);
    return (e2 - 1.f) / (e2 + 1.f);
}

// ---------- weight conversion: f32 -> f16 for the three big GEMM weights ----------
__global__ __launch_bounds__(256) void convw_kernel(
    const float* __restrict__ w0, const float* __restrict__ w1, const float* __restrict__ w2,
    _Float16* __restrict__ o0, _Float16* __restrict__ o1, _Float16* __restrict__ o2)
{
    const int i = blockIdx.x * 256 + threadIdx.x;
    if (i < N3H * KD) {
        o0[i] = (_Float16)w0[i];
        o1[i] = (_Float16)w1[i];
        o2[i] = (_Float16)w2[i];
    }
}

__global__ __launch_bounds__(256) void init_kernel(
    float* __restrict__ amp, float* __restrict__ phase,
    int* __restrict__ nup, int* __restrict__ ndn)
{
    const int i = blockIdx.x * 256 + threadIdx.x;
    if (i < BATCH) { amp[i] = 1.f; phase[i] = 0.f; nup[i] = 0; ndn[i] = 0; }
}

// ================= L1: z=0: gh0 GEMM + fused gates0 ; z=1: gh1 GEMM -> gB =================
// J-tiled: block covers 128 gate-channels x 3 gates (B-tile 384 rows). BM=128, BK=32.
// 512 threads = 8 waves (2m x 4j); per wave M=64, J=32; acc[4][2][3].
__global__ __launch_bounds__(512) void step1_kernel(
    const _Float16* __restrict__ h0h_c, const _Float16* __restrict__ h1h_c,
    const _Float16* __restrict__ wh0,   const _Float16* __restrict__ wh1,
    const float* __restrict__ Wih0, const int* __restrict__ bits,
    float* __restrict__ h0f, _Float16* __restrict__ h0h_n,
    _Float16* __restrict__ gB, int step)
{
    const int z = blockIdx.z;
    const _Float16* A = z ? h1h_c : h0h_c;
    const _Float16* W = z ? wh1 : wh0;
    const int j0 = blockIdx.x * 128;
    const int m0 = blockIdx.y * 128;

    __shared__ __align__(16) _Float16 As[128 * 32];
    __shared__ __align__(16) _Float16 Bs[384 * 32];

    const int tid  = threadIdx.x;
    const int lane = tid & 63;
    const int wid  = tid >> 6;
    const int wm   = wid >> 2, wj = wid & 3;

    floatx4 acc[4][2][3];
    const floatx4 z4 = {0.f, 0.f, 0.f, 0.f};
#pragma unroll
    for (int a = 0; a < 4; ++a)
#pragma unroll
        for (int b = 0; b < 2; ++b)
#pragma unroll
            for (int g = 0; g < 3; ++g) acc[a][b][g] = z4;

    // A staging: 512 16B-units, one per thread. XOR unit swizzle per tile row.
    const int ar  = tid >> 2;
    const int apu = (tid & 3) ^ ((ar >> 1) & 3);
    const _Float16* a_src = A + (size_t)(m0 + ar) * KD + apu * 8;
    // B staging: 1536 units, 3 per thread. Tile row -> global W row mapping.
    const _Float16* b_src[3];
#pragma unroll
    for (int k2 = 0; k2 < 3; ++k2) {
        const int u   = tid + k2 * 512;
        const int row = u >> 2;
        const int pu  = (u & 3) ^ ((row >> 1) & 3);
        const int grow = (row >> 7) * HID + j0 + (row & 127);
        b_src[k2] = W + (size_t)grow * KD + pu * 8;
    }
    uint4* asl = (uint4*)As;
    uint4* bsl = (uint4*)Bs;

    const int ku = lane >> 4;
    int aoff[4];
#pragma unroll
    for (int mf = 0; mf < 4; ++mf) {
        const int r = wm * 64 + mf * 16 + (lane & 15);
        aoff[mf] = r * 32 + ((ku ^ ((r >> 1) & 3)) * 8);
    }
    int boff[2][3];
#pragma unroll
    for (int jf = 0; jf < 2; ++jf)
#pragma unroll
        for (int g = 0; g < 3; ++g) {
            const int r = g * 128 + wj * 32 + jf * 16 + (lane & 15);
            boff[jf][g] = r * 32 + ((ku ^ ((r >> 1) & 3)) * 8);
        }

    for (int kt = 0; kt < 16; ++kt) {
        const int k0 = kt * 32;
        const uint4 ra  = *(const uint4*)(a_src + k0);
        const uint4 rb0 = *(const uint4*)(b_src[0] + k0);
        const uint4 rb1 = *(const uint4*)(b_src[1] + k0);
        const uint4 rb2 = *(const uint4*)(b_src[2] + k0);
        __syncthreads();
        asl[tid] = ra;
        bsl[tid] = rb0; bsl[tid + 512] = rb1; bsl[tid + 1024] = rb2;
        __syncthreads();
        half8 af[4], bf[2][3];
#pragma unroll
        for (int mf = 0; mf < 4; ++mf) af[mf] = *(const half8*)(As + aoff[mf]);
#pragma unroll
        for (int jf = 0; jf < 2; ++jf)
#pragma unroll
            for (int g = 0; g < 3; ++g) bf[jf][g] = *(const half8*)(Bs + boff[jf][g]);
#pragma unroll
        for (int mf = 0; mf < 4; ++mf)
#pragma unroll
            for (int jf = 0; jf < 2; ++jf)
#pragma unroll
                for (int g = 0; g < 3; ++g)
                    acc[mf][jf][g] = __builtin_amdgcn_mfma_f32_16x16x32_f16(af[mf], bf[jf][g], acc[mf][jf][g], 0, 0, 0);
    }

    if (z == 0) {
        // fused gates0: h0n = (1-z)*n + z*h0
#pragma unroll
        for (int mf = 0; mf < 4; ++mf)
#pragma unroll
            for (int jf = 0; jf < 2; ++jf) {
                const floatx4 gr = acc[mf][jf][0];
                const floatx4 gz = acc[mf][jf][1];
                const floatx4 gn = acc[mf][jf][2];
#pragma unroll
                for (int reg = 0; reg < 4; ++reg) {
                    const int m = m0 + wm * 64 + mf * 16 + (lane >> 4) * 4 + reg;
                    const int j = j0 + wj * 32 + jf * 16 + (lane & 15);
                    float gir = 0.f, giz = 0.f, gin = 0.f;
                    if (step > 0) {
                        const int t = bits[m * SORB + step - 1];
                        gir = Wih0[j * 2 + t];
                        giz = Wih0[(HID + j) * 2 + t];
                        gin = Wih0[(2 * HID + j) * 2 + t];
                    }
                    const float r  = sigmoidf_(gir + gr[reg]);
                    const float zz = sigmoidf_(giz + gz[reg]);
                    const float n  = tanhf_(gin + r * gn[reg]);
                    const size_t idx = (size_t)m * HID + j;
                    const float h  = h0f[idx];
                    const float hn = (1.f - zz) * n + zz * h;
                    h0f[idx]   = hn;
                    h0h_n[idx] = (_Float16)hn;
                }
            }
    } else {
        // plain write of gh1 into gB (standard [r|z|n] layout)
#pragma unroll
        for (int mf = 0; mf < 4; ++mf)
#pragma unroll
            for (int jf = 0; jf < 2; ++jf)
#pragma unroll
                for (int g = 0; g < 3; ++g)
#pragma unroll
                    for (int reg = 0; reg < 4; ++reg) {
                        const int m = m0 + wm * 64 + mf * 16 + (lane >> 4) * 4 + reg;
                        const int j = j0 + wj * 32 + jf * 16 + (lane & 15);
                        gB[(size_t)m * N3H + g * HID + j] = (_Float16)acc[mf][jf][g][reg];
                    }
    }
}

// ================= L2: gi1 GEMM + fused gates1 =================
// BM=64, J=128 (B-tile 384 rows). 512 threads = 8 waves (2m x 4j); wave M=32, J=32.
__global__ __launch_bounds__(512) void step2_kernel(
    const _Float16* __restrict__ h0h_n, const _Float16* __restrict__ wi1,
    const _Float16* __restrict__ gB,
    float* __restrict__ h1f, _Float16* __restrict__ h1h_n)
{
    const int j0 = blockIdx.x * 128;
    const int m0 = blockIdx.y * 64;

    __shared__ __align__(16) _Float16 As[64 * 32];
    __shared__ __align__(16) _Float16 Bs[384 * 32];

    const int tid  = threadIdx.x;
    const int lane = tid & 63;
    const int wid  = tid >> 6;
    const int wm   = wid >> 2, wj = wid & 3;

    floatx4 acc[2][2][3];
    const floatx4 z4 = {0.f, 0.f, 0.f, 0.f};
#pragma unroll
    for (int a = 0; a < 2; ++a)
#pragma unroll
        for (int b = 0; b < 2; ++b)
#pragma unroll
            for (int g = 0; g < 3; ++g) acc[a][b][g] = z4;

    const int ar  = tid >> 2;                    // valid for tid<256
    const int apu = (tid & 3) ^ ((ar >> 1) & 3);
    const _Float16* a_src = h0h_n + (size_t)(m0 + (ar & 63)) * KD + apu * 8;
    const _Float16* b_src[3];
#pragma unroll
    for (int k2 = 0; k2 < 3; ++k2) {
        const int u   = tid + k2 * 512;
        const int row = u >> 2;
        const int pu  = (u & 3) ^ ((row >> 1) & 3);
        const int grow = (row >> 7) * HID + j0 + (row & 127);
        b_src[k2] = wi1 + (size_t)grow * KD + pu * 8;
    }
    uint4* asl = (uint4*)As;
    uint4* bsl = (uint4*)Bs;

    const int ku = lane >> 4;
    int aoff[2];
#pragma unroll
    for (int mf = 0; mf < 2; ++mf) {
        const int r = wm * 32 + mf * 16 + (lane & 15);
        aoff[mf] = r * 32 + ((ku ^ ((r >> 1) & 3)) * 8);
    }
    int boff[2][3];
#pragma unroll
    for (int jf = 0; jf < 2; ++jf)
#pragma unroll
        for (int g = 0; g < 3; ++g) {
            const int r = g * 128 + wj * 32 + jf * 16 + (lane & 15);
            boff[jf][g] = r * 32 + ((ku ^ ((r >> 1) & 3)) * 8);
        }

    for (int kt = 0; kt < 16; ++kt) {
        const int k0 = kt * 32;
        uint4 ra = {0, 0, 0, 0};
        if (tid < 256) ra = *(const uint4*)(a_src + k0);
        const uint4 rb0 = *(const uint4*)(b_src[0] + k0);
        const uint4 rb1 = *(const uint4*)(b_src[1] + k0);
        const uint4 rb2 = *(const uint4*)(b_src[2] + k0);
        __syncthreads();
        if (tid < 256) asl[tid] = ra;
        bsl[tid] = rb0; bsl[tid + 512] = rb1; bsl[tid + 1024] = rb2;
        __syncthreads();
        half8 af[2], bf[2][3];
#pragma unroll
        for (int mf = 0; mf < 2; ++mf) af[mf] = *(const half8*)(As + aoff[mf]);
#pragma unroll
        for (int jf = 0; jf < 2; ++jf)
#pragma unroll
            for (int g = 0; g < 3; ++g) bf[jf][g] = *(const half8*)(Bs + boff[jf][g]);
#pragma unroll
        for (int mf = 0; mf < 2; ++mf)
#pragma unroll
            for (int jf = 0; jf < 2; ++jf)
#pragma unroll
                for (int g = 0; g < 3; ++g)
                    acc[mf][jf][g] = __builtin_amdgcn_mfma_f32_16x16x32_f16(af[mf], bf[jf][g], acc[mf][jf][g], 0, 0, 0);
    }

    // fused gates1: h1n = (1-z)*n + z*h1  (gh1 comes from gB)
#pragma unroll
    for (int mf = 0; mf < 2; ++mf)
#pragma unroll
        for (int jf = 0; jf < 2; ++jf) {
            const floatx4 gr = acc[mf][jf][0];
            const floatx4 gz = acc[mf][jf][1];
            const floatx4 gn = acc[mf][jf][2];
#pragma unroll
            for (int reg = 0; reg < 4; ++reg) {
                const int m = m0 + wm * 32 + mf * 16 + (lane >> 4) * 4 + reg;
                const int j = j0 + wj * 32 + jf * 16 + (lane & 15);
                const size_t gbase = (size_t)m * N3H;
                const float ghr = (float)gB[gbase + j];
                const float ghz = (float)gB[gbase + HID + j];
                const float ghn = (float)gB[gbase + 2 * HID + j];
                const float r  = sigmoidf_(gr[reg] + ghr);
                const float zz = sigmoidf_(gz[reg] + ghz);
                const float n  = tanhf_(gn[reg] + r * ghn);
                const size_t idx = (size_t)m * HID + j;
                const float h  = h1f[idx];
                const float hn = (1.f - zz) * n + zz * h;
                h1f[idx]   = hn;
                h1h_n[idx] = (_Float16)hn;
            }
        }
}

// ================= L3: heads + accumulation. One wave per batch row. =================
__global__ __launch_bounds__(256) void head_kernel(
    const _Float16* __restrict__ h1h_n,
    const float* __restrict__ Wamp, const float* __restrict__ bamp,
    const float* __restrict__ Wph,  const float* __restrict__ bph,
    const int* __restrict__ bits,
    float* __restrict__ amp, float* __restrict__ phase,
    int* __restrict__ nup, int* __restrict__ ndn,
    float* __restrict__ out, int step)
{
    const int lane = threadIdx.x & 63;
    const int m    = blockIdx.x * 4 + (threadIdx.x >> 6);
    const half8 hv = *(const half8*)(h1h_n + (size_t)m * HID + lane * 8);
    float d0 = 0.f, d1 = 0.f, d2 = 0.f, d3 = 0.f;
#pragma unroll
    for (int e = 0; e < 8; ++e) {
        const int j = lane * 8 + e;
        const float hn = (float)hv[e];
        d0 += hn * Wamp[j];       d1 += hn * Wamp[HID + j];
        d2 += hn * Wph[j];        d3 += hn * Wph[HID + j];
    }
#pragma unroll
    for (int off = 1; off < 64; off <<= 1) {
        d0 += __shfl_xor(d0, off); d1 += __shfl_xor(d1, off);
        d2 += __shfl_xor(d2, off); d3 += __shfl_xor(d3, off);
    }
    if (lane == 0) {
        const float a0 = d0 + bamp[0];
        const float a1 = d1 + bamp[1];
        const float mx = fmaxf(a0, a1);
        const float e0 = __expf(a0 - mx), e1 = __expf(a1 - mx);
        const float inv = 1.f / (e0 + e1);
        float ya0 = sqrtf(e0 * inv), ya1 = sqrtf(e1 * inv);
        const float p0 = d2 + bph[0];
        const float p1 = d3 + bph[1];
        const float yp0 = PI_F * p0 / (1.f + fabsf(p0));
        const float yp1 = PI_F * p1 / (1.f + fabsf(p1));
        const int even = ((step & 1) == 0);
        const int cnt = even ? nup[m] : ndn[m];
        if (step >= 32) {  // MIN_I
            const int lower = (step >> 1) - 16;
            const float m0v = (cnt > lower) ? ya0 : 0.f;
            const float m1v = (cnt < 16) ? ya1 : 0.f;
            const float nrm = sqrtf(m0v * m0v + m1v * m1v + 1e-12f);
            ya0 = m0v / nrm; ya1 = m1v / nrm;
        }
        const int bi = bits[m * SORB + step];
        const float na = amp[m] * (bi ? ya1 : ya0);
        const float np = phase[m] + (bi ? yp1 : yp0);
        amp[m] = na; phase[m] = np;
        if (bi) { if (even) nup[m] = cnt + 1; else ndn[m] = cnt + 1; }
        if (step == SORB - 1) {
            out[m * 2 + 0] = na;
            out[m * 2 + 1] = np;
        }
    }
}

extern "C" void kernel_launch(void* const* d_in, const int* in_sizes, int n_in,
                              void* d_out, int out_size, void* d_ws, size_t ws_size,
                              hipStream_t stream) {
    const int*   bits = (const int*)d_in[0];
    const float* Wih0 = (const float*)d_in[1];
    const float* Whh0 = (const float*)d_in[2];
    const float* Wih1 = (const float*)d_in[3];
    const float* Whh1 = (const float*)d_in[4];
    const float* Wamp = (const float*)d_in[5];
    const float* bamp = (const float*)d_in[6];
    const float* Wph  = (const float*)d_in[7];
    const float* bph  = (const float*)d_in[8];
    float* out = (float*)d_out;

    char* ws = (char*)d_ws;
    size_t off = 0;
    auto alloc = [&](size_t bytes) {
        void* p = ws + off;
        off = (off + bytes + 255) & ~(size_t)255;
        return p;
    };
    _Float16* wh0 = (_Float16*)alloc((size_t)N3H * KD * 2);
    _Float16* wi1 = (_Float16*)alloc((size_t)N3H * KD * 2);
    _Float16* wh1 = (_Float16*)alloc((size_t)N3H * KD * 2);
    float*    h0f = (float*)alloc((size_t)BATCH * HID * 4);
    float*    h1f = (float*)alloc((size_t)BATCH * HID * 4);
    _Float16* h0hA = (_Float16*)alloc((size_t)BATCH * HID * 2);
    _Float16* h0hB = (_Float16*)alloc((size_t)BATCH * HID * 2);
    _Float16* h1hA = (_Float16*)alloc((size_t)BATCH * HID * 2);
    _Float16* h1hB = (_Float16*)alloc((size_t)BATCH * HID * 2);
    _Float16* gB  = (_Float16*)alloc((size_t)BATCH * N3H * 2);
    float*    amp   = (float*)alloc((size_t)BATCH * 4);
    float*    phase = (float*)alloc((size_t)BATCH * 4);
    int*      nup   = (int*)alloc((size_t)BATCH * 4);
    int*      ndn   = (int*)alloc((size_t)BATCH * 4);

    _Float16* h0h[2] = {h0hA, h0hB};
    _Float16* h1h[2] = {h1hA, h1hB};

    hipMemsetAsync(h0f, 0, (size_t)BATCH * HID * 4, stream);
    hipMemsetAsync(h1f, 0, (size_t)BATCH * HID * 4, stream);
    hipMemsetAsync(h0hA, 0, (size_t)BATCH * HID * 2, stream);
    hipMemsetAsync(h1hA, 0, (size_t)BATCH * HID * 2, stream);
    convw_kernel<<<(N3H * KD + 255) / 256, 256, 0, stream>>>(Whh0, Wih1, Whh1, wh0, wi1, wh1);
    init_kernel<<<BATCH / 256, 256, 0, stream>>>(amp, phase, nup, ndn);

    for (int s = 0; s < SORB; ++s) {
        const int cur = s & 1, nxt = cur ^ 1;
        step1_kernel<<<dim3(4, 32, 2), 512, 0, stream>>>(
            h0h[cur], h1h[cur], wh0, wh1, Wih0, bits, h0f, h0h[nxt], gB, s);
        step2_kernel<<<dim3(4, 64, 1), 512, 0, stream>>>(
            h0h[nxt], wi1, gB, h1f, h1h[nxt]);
        head_kernel<<<BATCH / 4, 256, 0, stream>>>(
            h1h[nxt], Wamp, bamp, Wph, bph, bits, amp, phase, nup, ndn, out, s);
    }
}

// Round 10
// 3615.108 us; speedup vs baseline: 1.1373x; 1.1373x over previous
//
#include <hip/hip_runtime.h>
#include <hip/hip_bf16.h>

#define SORB  64
#define HID   512
#define BATCH 4096
#define N3H   1536   // 3*HID
#define KD    512
#define PI_F  3.14159265358979f

typedef _Float16 half8 __attribute__((ext_vector_type(8)));
typedef float    floatx4 __attribute__((ext_vector_type(4)));

__device__ __forceinline__ float sigmoidf_(float x) { return 1.f / (1.f + __expf(-x)); }
__device__ __forceinline__ float tanhf_(float x) {
    x = fminf(fmaxf(x, -15.f), 15.f);
    const float e2 = __expf(2.f * x);
    return (e2 - 1.f) / (e2 + 1.f);
}

__global__ __launch_bounds__(256) void convw_kernel(
    const float* __restrict__ w0, const float* __restrict__ w1, const float* __restrict__ w2,
    _Float16* __restrict__ o0, _Float16* __restrict__ o1, _Float16* __restrict__ o2)
{
    const int i = blockIdx.x * 256 + threadIdx.x;
    if (i < N3H * KD) {
        o0[i] = (_Float16)w0[i];
        o1[i] = (_Float16)w1[i];
        o2[i] = (_Float16)w2[i];
    }
}

__global__ __launch_bounds__(256) void init_kernel(
    float* __restrict__ amp, float* __restrict__ phase,
    int* __restrict__ nup, int* __restrict__ ndn)
{
    const int i = blockIdx.x * 256 + threadIdx.x;
    if (i < BATCH) { amp[i] = 1.f; phase[i] = 0.f; nup[i] = 0; ndn[i] = 0; }
}

// ================= L1: z=0: gh0 GEMM + fused gates0 ; z=1: gh1 GEMM -> gB =================
// BM=64, J=64 (B-tile 192 rows), BK=32. 256 threads = 4 waves (2m x 2j);
// wave M=32, J=32; acc[2][2][3]. Grid (8, 64, 2) = 1024 blocks.
__global__ __launch_bounds__(256) void step1_kernel(
    const _Float16* __restrict__ h0h_c, const _Float16* __restrict__ h1h_c,
    const _Float16* __restrict__ wh0,   const _Float16* __restrict__ wh1,
    const float* __restrict__ Wih0, const int* __restrict__ bits,
    float* __restrict__ h0f, _Float16* __restrict__ h0h_n,
    _Float16* __restrict__ gB, int step)
{
    const int z = blockIdx.z;
    const _Float16* A = z ? h1h_c : h0h_c;
    const _Float16* W = z ? wh1 : wh0;
    const int j0 = blockIdx.x * 64;
    const int m0 = blockIdx.y * 64;

    __shared__ __align__(16) _Float16 As[64 * 32];
    __shared__ __align__(16) _Float16 Bs[192 * 32];

    const int tid  = threadIdx.x;
    const int lane = tid & 63;
    const int wid  = tid >> 6;
    const int wm   = wid >> 1, wj = wid & 1;

    floatx4 acc[2][2][3];
    const floatx4 z4 = {0.f, 0.f, 0.f, 0.f};
#pragma unroll
    for (int a = 0; a < 2; ++a)
#pragma unroll
        for (int b = 0; b < 2; ++b)
#pragma unroll
            for (int g = 0; g < 3; ++g) acc[a][b][g] = z4;

    // A staging: 256 16B-units (1/thread), XOR unit swizzle per row.
    const int ar  = tid >> 2;
    const int apu = (tid & 3) ^ ((ar >> 1) & 3);
    const _Float16* a_src = A + (size_t)(m0 + ar) * KD + apu * 8;
    // B staging: 768 units (3/thread). Tile row r: gate g=r/64, channel j0+(r%64).
    const _Float16* b_src[3];
#pragma unroll
    for (int k2 = 0; k2 < 3; ++k2) {
        const int u   = tid + k2 * 256;
        const int row = u >> 2;
        const int pu  = (u & 3) ^ ((row >> 1) & 3);
        const int grow = (row >> 6) * HID + j0 + (row & 63);
        b_src[k2] = W + (size_t)grow * KD + pu * 8;
    }
    uint4* asl = (uint4*)As;
    uint4* bsl = (uint4*)Bs;

    const int ku = lane >> 4;
    int aoff[2];
#pragma unroll
    for (int mf = 0; mf < 2; ++mf) {
        const int r = wm * 32 + mf * 16 + (lane & 15);
        aoff[mf] = r * 32 + ((ku ^ ((r >> 1) & 3)) * 8);
    }
    int boff[2][3];
#pragma unroll
    for (int jf = 0; jf < 2; ++jf)
#pragma unroll
        for (int g = 0; g < 3; ++g) {
            const int r = g * 64 + wj * 32 + jf * 16 + (lane & 15);
            boff[jf][g] = r * 32 + ((ku ^ ((r >> 1) & 3)) * 8);
        }

    for (int kt = 0; kt < 16; ++kt) {
        const int k0 = kt * 32;
        const uint4 ra  = *(const uint4*)(a_src + k0);
        const uint4 rb0 = *(const uint4*)(b_src[0] + k0);
        const uint4 rb1 = *(const uint4*)(b_src[1] + k0);
        const uint4 rb2 = *(const uint4*)(b_src[2] + k0);
        __syncthreads();
        asl[tid] = ra;
        bsl[tid] = rb0; bsl[tid + 256] = rb1; bsl[tid + 512] = rb2;
        __syncthreads();
        half8 af[2], bf[2][3];
#pragma unroll
        for (int mf = 0; mf < 2; ++mf) af[mf] = *(const half8*)(As + aoff[mf]);
#pragma unroll
        for (int jf = 0; jf < 2; ++jf)
#pragma unroll
            for (int g = 0; g < 3; ++g) bf[jf][g] = *(const half8*)(Bs + boff[jf][g]);
#pragma unroll
        for (int mf = 0; mf < 2; ++mf)
#pragma unroll
            for (int jf = 0; jf < 2; ++jf)
#pragma unroll
                for (int g = 0; g < 3; ++g)
                    acc[mf][jf][g] = __builtin_amdgcn_mfma_f32_16x16x32_f16(af[mf], bf[jf][g], acc[mf][jf][g], 0, 0, 0);
    }

    if (z == 0) {
        // fused gates0: h0n = (1-z)*n + z*h0
#pragma unroll
        for (int mf = 0; mf < 2; ++mf)
#pragma unroll
            for (int jf = 0; jf < 2; ++jf) {
                const floatx4 gr = acc[mf][jf][0];
                const floatx4 gz = acc[mf][jf][1];
                const floatx4 gn = acc[mf][jf][2];
#pragma unroll
                for (int reg = 0; reg < 4; ++reg) {
                    const int m = m0 + wm * 32 + mf * 16 + (lane >> 4) * 4 + reg;
                    const int j = j0 + wj * 32 + jf * 16 + (lane & 15);
                    float gir = 0.f, giz = 0.f, gin = 0.f;
                    if (step > 0) {
                        const int t = bits[m * SORB + step - 1];
                        gir = Wih0[j * 2 + t];
                        giz = Wih0[(HID + j) * 2 + t];
                        gin = Wih0[(2 * HID + j) * 2 + t];
                    }
                    const float r  = sigmoidf_(gir + gr[reg]);
                    const float zz = sigmoidf_(giz + gz[reg]);
                    const float n  = tanhf_(gin + r * gn[reg]);
                    const size_t idx = (size_t)m * HID + j;
                    const float h  = h0f[idx];
                    const float hn = (1.f - zz) * n + zz * h;
                    h0f[idx]   = hn;
                    h0h_n[idx] = (_Float16)hn;
                }
            }
    } else {
#pragma unroll
        for (int mf = 0; mf < 2; ++mf)
#pragma unroll
            for (int jf = 0; jf < 2; ++jf)
#pragma unroll
                for (int g = 0; g < 3; ++g)
#pragma unroll
                    for (int reg = 0; reg < 4; ++reg) {
                        const int m = m0 + wm * 32 + mf * 16 + (lane >> 4) * 4 + reg;
                        const int j = j0 + wj * 32 + jf * 16 + (lane & 15);
                        gB[(size_t)m * N3H + g * HID + j] = (_Float16)acc[mf][jf][g][reg];
                    }
    }
}

// ================= L2: gi1 GEMM + fused gates1 =================
// Same tile geometry as step1. Grid (8, 64) = 512 blocks.
__global__ __launch_bounds__(256) void step2_kernel(
    const _Float16* __restrict__ h0h_n, const _Float16* __restrict__ wi1,
    const _Float16* __restrict__ gB,
    float* __restrict__ h1f, _Float16* __restrict__ h1h_n)
{
    const int j0 = blockIdx.x * 64;
    const int m0 = blockIdx.y * 64;

    __shared__ __align__(16) _Float16 As[64 * 32];
    __shared__ __align__(16) _Float16 Bs[192 * 32];

    const int tid  = threadIdx.x;
    const int lane = tid & 63;
    const int wid  = tid >> 6;
    const int wm   = wid >> 1, wj = wid & 1;

    floatx4 acc[2][2][3];
    const floatx4 z4 = {0.f, 0.f, 0.f, 0.f};
#pragma unroll
    for (int a = 0; a < 2; ++a)
#pragma unroll
        for (int b = 0; b < 2; ++b)
#pragma unroll
            for (int g = 0; g < 3; ++g) acc[a][b][g] = z4;

    const int ar  = tid >> 2;
    const int apu = (tid & 3) ^ ((ar >> 1) & 3);
    const _Float16* a_src = h0h_n + (size_t)(m0 + ar) * KD + apu * 8;
    const _Float16* b_src[3];
#pragma unroll
    for (int k2 = 0; k2 < 3; ++k2) {
        const int u   = tid + k2 * 256;
        const int row = u >> 2;
        const int pu  = (u & 3) ^ ((row >> 1) & 3);
        const int grow = (row >> 6) * HID + j0 + (row & 63);
        b_src[k2] = wi1 + (size_t)grow * KD + pu * 8;
    }
    uint4* asl = (uint4*)As;
    uint4* bsl = (uint4*)Bs;

    const int ku = lane >> 4;
    int aoff[2];
#pragma unroll
    for (int mf = 0; mf < 2; ++mf) {
        const int r = wm * 32 + mf * 16 + (lane & 15);
        aoff[mf] = r * 32 + ((ku ^ ((r >> 1) & 3)) * 8);
    }
    int boff[2][3];
#pragma unroll
    for (int jf = 0; jf < 2; ++jf)
#pragma unroll
        for (int g = 0; g < 3; ++g) {
            const int r = g * 64 + wj * 32 + jf * 16 + (lane & 15);
            boff[jf][g] = r * 32 + ((ku ^ ((r >> 1) & 3)) * 8);
        }

    for (int kt = 0; kt < 16; ++kt) {
        const int k0 = kt * 32;
        const uint4 ra  = *(const uint4*)(a_src + k0);
        const uint4 rb0 = *(const uint4*)(b_src[0] + k0);
        const uint4 rb1 = *(const uint4*)(b_src[1] + k0);
        const uint4 rb2 = *(const uint4*)(b_src[2] + k0);
        __syncthreads();
        asl[tid] = ra;
        bsl[tid] = rb0; bsl[tid + 256] = rb1; bsl[tid + 512] = rb2;
        __syncthreads();
        half8 af[2], bf[2][3];
#pragma unroll
        for (int mf = 0; mf < 2; ++mf) af[mf] = *(const half8*)(As + aoff[mf]);
#pragma unroll
        for (int jf = 0; jf < 2; ++jf)
#pragma unroll
            for (int g = 0; g < 3; ++g) bf[jf][g] = *(const half8*)(Bs + boff[jf][g]);
#pragma unroll
        for (int mf = 0; mf < 2; ++mf)
#pragma unroll
            for (int jf = 0; jf < 2; ++jf)
#pragma unroll
                for (int g = 0; g < 3; ++g)
                    acc[mf][jf][g] = __builtin_amdgcn_mfma_f32_16x16x32_f16(af[mf], bf[jf][g], acc[mf][jf][g], 0, 0, 0);
    }

    // fused gates1: h1n = (1-z)*n + z*h1  (gh1 from gB)
#pragma unroll
    for (int mf = 0; mf < 2; ++mf)
#pragma unroll
        for (int jf = 0; jf < 2; ++jf) {
            const floatx4 gr = acc[mf][jf][0];
            const floatx4 gz = acc[mf][jf][1];
            const floatx4 gn = acc[mf][jf][2];
#pragma unroll
            for (int reg = 0; reg < 4; ++reg) {
                const int m = m0 + wm * 32 + mf * 16 + (lane >> 4) * 4 + reg;
                const int j = j0 + wj * 32 + jf * 16 + (lane & 15);
                const size_t gbase = (size_t)m * N3H;
                const float ghr = (float)gB[gbase + j];
                const float ghz = (float)gB[gbase + HID + j];
                const float ghn = (float)gB[gbase + 2 * HID + j];
                const float r  = sigmoidf_(gr[reg] + ghr);
                const float zz = sigmoidf_(gz[reg] + ghz);
                const float n  = tanhf_(gn[reg] + r * ghn);
                const size_t idx = (size_t)m * HID + j;
                const float h  = h1f[idx];
                const float hn = (1.f - zz) * n + zz * h;
                h1f[idx]   = hn;
                h1h_n[idx] = (_Float16)hn;
            }
        }
}

// ================= L3: heads + accumulation. One wave per batch row. =================
__global__ __launch_bounds__(256) void head_kernel(
    const _Float16* __restrict__ h1h_n,
    const float* __restrict__ Wamp, const float* __restrict__ bamp,
    const float* __restrict__ Wph,  const float* __restrict__ bph,
    const int* __restrict__ bits,
    float* __restrict__ amp, float* __restrict__ phase,
    int* __restrict__ nup, int* __restrict__ ndn,
    float* __restrict__ out, int step)
{
    const int lane = threadIdx.x & 63;
    const int m    = blockIdx.x * 4 + (threadIdx.x >> 6);
    const half8 hv = *(const half8*)(h1h_n + (size_t)m * HID + lane * 8);
    float d0 = 0.f, d1 = 0.f, d2 = 0.f, d3 = 0.f;
#pragma unroll
    for (int e = 0; e < 8; ++e) {
        const int j = lane * 8 + e;
        const float hn = (float)hv[e];
        d0 += hn * Wamp[j];       d1 += hn * Wamp[HID + j];
        d2 += hn * Wph[j];        d3 += hn * Wph[HID + j];
    }
#pragma unroll
    for (int off = 1; off < 64; off <<= 1) {
        d0 += __shfl_xor(d0, off); d1 += __shfl_xor(d1, off);
        d2 += __shfl_xor(d2, off); d3 += __shfl_xor(d3, off);
    }
    if (lane == 0) {
        const float a0 = d0 + bamp[0];
        const float a1 = d1 + bamp[1];
        const float mx = fmaxf(a0, a1);
        const float e0 = __expf(a0 - mx), e1 = __expf(a1 - mx);
        const float inv = 1.f / (e0 + e1);
        float ya0 = sqrtf(e0 * inv), ya1 = sqrtf(e1 * inv);
        const float p0 = d2 + bph[0];
        const float p1 = d3 + bph[1];
        const float yp0 = PI_F * p0 / (1.f + fabsf(p0));
        const float yp1 = PI_F * p1 / (1.f + fabsf(p1));
        const int even = ((step & 1) == 0);
        const int cnt = even ? nup[m] : ndn[m];
        if (step >= 32) {  // MIN_I
            const int lower = (step >> 1) - 16;
            const float m0v = (cnt > lower) ? ya0 : 0.f;
            const float m1v = (cnt < 16) ? ya1 : 0.f;
            const float nrm = sqrtf(m0v * m0v + m1v * m1v + 1e-12f);
            ya0 = m0v / nrm; ya1 = m1v / nrm;
        }
        const int bi = bits[m * SORB + step];
        const float na = amp[m] * (bi ? ya1 : ya0);
        const float np = phase[m] + (bi ? yp1 : yp0);
        amp[m] = na; phase[m] = np;
        if (bi) { if (even) nup[m] = cnt + 1; else ndn[m] = cnt + 1; }
        if (step == SORB - 1) {
            out[m * 2 + 0] = na;
            out[m * 2 + 1] = np;
        }
    }
}

extern "C" void kernel_launch(void* const* d_in, const int* in_sizes, int n_in,
                              void* d_out, int out_size, void* d_ws, size_t ws_size,
                              hipStream_t stream) {
    const int*   bits = (const int*)d_in[0];
    const float* Wih0 = (const float*)d_in[1];
    const float* Whh0 = (const float*)d_in[2];
    const float* Wih1 = (const float*)d_in[3];
    const float* Whh1 = (const float*)d_in[4];
    const float* Wamp = (const float*)d_in[5];
    const float* bamp = (const float*)d_in[6];
    const float* Wph  = (const float*)d_in[7];
    const float* bph  = (const float*)d_in[8];
    float* out = (float*)d_out;

    char* ws = (char*)d_ws;
    size_t off = 0;
    auto alloc = [&](size_t bytes) {
        void* p = ws + off;
        off = (off + bytes + 255) & ~(size_t)255;
        return p;
    };
    _Float16* wh0 = (_Float16*)alloc((size_t)N3H * KD * 2);
    _Float16* wi1 = (_Float16*)alloc((size_t)N3H * KD * 2);
    _Float16* wh1 = (_Float16*)alloc((size_t)N3H * KD * 2);
    float*    h0f = (float*)alloc((size_t)BATCH * HID * 4);
    float*    h1f = (float*)alloc((size_t)BATCH * HID * 4);
    _Float16* h0hA = (_Float16*)alloc((size_t)BATCH * HID * 2);
    _Float16* h0hB = (_Float16*)alloc((size_t)BATCH * HID * 2);
    _Float16* h1hA = (_Float16*)alloc((size_t)BATCH * HID * 2);
    _Float16* h1hB = (_Float16*)alloc((size_t)BATCH * HID * 2);
    _Float16* gB  = (_Float16*)alloc((size_t)BATCH * N3H * 2);
    float*    amp   = (float*)alloc((size_t)BATCH * 4);
    float*    phase = (float*)alloc((size_t)BATCH * 4);
    int*      nup   = (int*)alloc((size_t)BATCH * 4);
    int*      ndn   = (int*)alloc((size_t)BATCH * 4);

    _Float16* h0h[2] = {h0hA, h0hB};
    _Float16* h1h[2] = {h1hA, h1hB};

    hipMemsetAsync(h0f, 0, (size_t)BATCH * HID * 4, stream);
    hipMemsetAsync(h1f, 0, (size_t)BATCH * HID * 4, stream);
    hipMemsetAsync(h0hA, 0, (size_t)BATCH * HID * 2, stream);
    hipMemsetAsync(h1hA, 0, (size_t)BATCH * HID * 2, stream);
    convw_kernel<<<(N3H * KD + 255) / 256, 256, 0, stream>>>(Whh0, Wih1, Whh1, wh0, wi1, wh1);
    init_kernel<<<BATCH / 256, 256, 0, stream>>>(amp, phase, nup, ndn);

    for (int s = 0; s < SORB; ++s) {
        const int cur = s & 1, nxt = cur ^ 1;
        step1_kernel<<<dim3(8, 64, 2), 256, 0, stream>>>(
            h0h[cur], h1h[cur], wh0, wh1, Wih0, bits, h0f, h0h[nxt], gB, s);
        step2_kernel<<<dim3(8, 64, 1), 256, 0, stream>>>(
            h0h[nxt], wi1, gB, h1f, h1h[nxt]);
        head_kernel<<<BATCH / 4, 256, 0, stream>>>(
            h1h[nxt], Wamp, bamp, Wph, bph, bits, amp, phase, nup, ndn, out, s);
    }
}

// Round 11
// 3306.522 us; speedup vs baseline: 1.2434x; 1.0933x over previous
//
#include <hip/hip_runtime.h>
#include <hip/hip_bf16.h>

#define SORB  64
#define HID   512
#define BATCH 4096
#define N3H   1536   // 3*HID
#define KD    512
#define BK    64
#define PI_F  3.14159265358979f

typedef _Float16 half8 __attribute__((ext_vector_type(8)));
typedef float    floatx4 __attribute__((ext_vector_type(4)));

__device__ __forceinline__ void gload16(const void* g, void* l) {
    __builtin_amdgcn_global_load_lds(
        (const __attribute__((address_space(1))) void*)g,
        (__attribute__((address_space(3))) void*)l, 16, 0, 0);
}

__device__ __forceinline__ float sigmoidf_(float x) { return 1.f / (1.f + __expf(-x)); }
__device__ __forceinline__ float tanhf_(float x) {
    x = fminf(fmaxf(x, -15.f), 15.f);
    const float e2 = __expf(2.f * x);
    return (e2 - 1.f) / (e2 + 1.f);
}

__global__ __launch_bounds__(256) void convw_kernel(
    const float* __restrict__ w0, const float* __restrict__ w1, const float* __restrict__ w2,
    _Float16* __restrict__ o0, _Float16* __restrict__ o1, _Float16* __restrict__ o2)
{
    const int i = blockIdx.x * 256 + threadIdx.x;
    if (i < N3H * KD) {
        o0[i] = (_Float16)w0[i];
        o1[i] = (_Float16)w1[i];
        o2[i] = (_Float16)w2[i];
    }
}

__global__ __launch_bounds__(256) void init_kernel(
    float* __restrict__ amp, float* __restrict__ phase,
    int* __restrict__ nup, int* __restrict__ ndn)
{
    const int i = blockIdx.x * 256 + threadIdx.x;
    if (i < BATCH) { amp[i] = 1.f; phase[i] = 0.f; nup[i] = 0; ndn[i] = 0; }
}

// LDS tile layout (BK=64, 8 x 16B-units per row): phys slot (row, c) holds
// global unit (row, c ^ (row&7)).  Fragment read of logical unit u at row r
// reads phys c = u ^ (r&7): every 16-lane group spreads over all 8 unit
// columns -> 2 lanes/bank = conflict-free.

// ================= L1: z=0: gh0 GEMM + fused gates0 ; z=1: gh1 GEMM -> gB =================
// BM=64, J=64 (B-tile 192 rows), BK=64. 256 threads = 4 waves (2m x 2j).
// Staging via global_load_lds(16B): LDS dest linear, swizzle on global source.
__global__ __launch_bounds__(256) void step1_kernel(
    const _Float16* __restrict__ h0h_c, const _Float16* __restrict__ h1h_c,
    const _Float16* __restrict__ wh0,   const _Float16* __restrict__ wh1,
    const float* __restrict__ Wih0, const int* __restrict__ bits,
    float* __restrict__ h0f, _Float16* __restrict__ h0h_n,
    _Float16* __restrict__ gB, int step)
{
    const int z = blockIdx.z;
    const _Float16* A = z ? h1h_c : h0h_c;
    const _Float16* W = z ? wh1 : wh0;
    const int j0 = blockIdx.x * 64;
    const int m0 = blockIdx.y * 64;

    __shared__ __align__(16) _Float16 As[64 * BK];    // 8 KB
    __shared__ __align__(16) _Float16 Bs[192 * BK];   // 24 KB

    const int tid  = threadIdx.x;
    const int lane = tid & 63;
    const int wid  = tid >> 6;
    const int wm   = wid >> 1, wj = wid & 1;

    floatx4 acc[2][2][3];
    const floatx4 z4 = {0.f, 0.f, 0.f, 0.f};
#pragma unroll
    for (int a = 0; a < 2; ++a)
#pragma unroll
        for (int b = 0; b < 2; ++b)
#pragma unroll
            for (int g = 0; g < 3; ++g) acc[a][b][g] = z4;

    // staging sources: thread tid covers LDS slots tid + k2*256
    const _Float16* a_srcp[2];
#pragma unroll
    for (int k2 = 0; k2 < 2; ++k2) {
        const int p = tid + k2 * 256, row = p >> 3, c = (p & 7) ^ (row & 7);
        a_srcp[k2] = A + (size_t)(m0 + row) * KD + c * 8;
    }
    const _Float16* b_srcp[6];
#pragma unroll
    for (int k2 = 0; k2 < 6; ++k2) {
        const int p = tid + k2 * 256, row = p >> 3, c = (p & 7) ^ (row & 7);
        const int grow = (row >> 6) * HID + j0 + (row & 63);
        b_srcp[k2] = W + (size_t)grow * KD + c * 8;
    }
    // wave-uniform LDS dests (lane offset applied by hardware)
    _Float16* a_dst[2];
#pragma unroll
    for (int k2 = 0; k2 < 2; ++k2) a_dst[k2] = As + (size_t)(k2 * 256 + wid * 64) * 8;
    _Float16* b_dst[6];
#pragma unroll
    for (int k2 = 0; k2 < 6; ++k2) b_dst[k2] = Bs + (size_t)(k2 * 256 + wid * 64) * 8;

    // fragment element offsets: r*BK + ((u ^ (r&7))*8), u = kk*4 + ku
    const int ku = lane >> 4;
    int aoff[2][2], boff[2][3][2];
#pragma unroll
    for (int mf = 0; mf < 2; ++mf) {
        const int r = wm * 32 + mf * 16 + (lane & 15);
#pragma unroll
        for (int kk = 0; kk < 2; ++kk)
            aoff[mf][kk] = r * BK + (((kk * 4 + ku) ^ (r & 7)) * 8);
    }
#pragma unroll
    for (int jf = 0; jf < 2; ++jf)
#pragma unroll
        for (int g = 0; g < 3; ++g) {
            const int r = g * 64 + wj * 32 + jf * 16 + (lane & 15);
#pragma unroll
            for (int kk = 0; kk < 2; ++kk)
                boff[jf][g][kk] = r * BK + (((kk * 4 + ku) ^ (r & 7)) * 8);
        }

    for (int kt = 0; kt < 8; ++kt) {
        const int k0 = kt * BK;
#pragma unroll
        for (int k2 = 0; k2 < 2; ++k2) gload16(a_srcp[k2] + k0, a_dst[k2]);
#pragma unroll
        for (int k2 = 0; k2 < 6; ++k2) gload16(b_srcp[k2] + k0, b_dst[k2]);
        __syncthreads();   // drains vmcnt, loads visible
#pragma unroll
        for (int kk = 0; kk < 2; ++kk) {
            half8 af[2], bf[2][3];
#pragma unroll
            for (int mf = 0; mf < 2; ++mf) af[mf] = *(const half8*)(As + aoff[mf][kk]);
#pragma unroll
            for (int jf = 0; jf < 2; ++jf)
#pragma unroll
                for (int g = 0; g < 3; ++g) bf[jf][g] = *(const half8*)(Bs + boff[jf][g][kk]);
#pragma unroll
            for (int mf = 0; mf < 2; ++mf)
#pragma unroll
                for (int jf = 0; jf < 2; ++jf)
#pragma unroll
                    for (int g = 0; g < 3; ++g)
                        acc[mf][jf][g] = __builtin_amdgcn_mfma_f32_16x16x32_f16(af[mf], bf[jf][g], acc[mf][jf][g], 0, 0, 0);
        }
        __syncthreads();   // reads done before next overwrite
    }

    if (z == 0) {
        // fused gates0: h0n = (1-z)*n + z*h0
#pragma unroll
        for (int mf = 0; mf < 2; ++mf)
#pragma unroll
            for (int jf = 0; jf < 2; ++jf) {
                const floatx4 gr = acc[mf][jf][0];
                const floatx4 gz = acc[mf][jf][1];
                const floatx4 gn = acc[mf][jf][2];
#pragma unroll
                for (int reg = 0; reg < 4; ++reg) {
                    const int m = m0 + wm * 32 + mf * 16 + (lane >> 4) * 4 + reg;
                    const int j = j0 + wj * 32 + jf * 16 + (lane & 15);
                    float gir = 0.f, giz = 0.f, gin = 0.f;
                    if (step > 0) {
                        const int t = bits[m * SORB + step - 1];
                        gir = Wih0[j * 2 + t];
                        giz = Wih0[(HID + j) * 2 + t];
                        gin = Wih0[(2 * HID + j) * 2 + t];
                    }
                    const float r  = sigmoidf_(gir + gr[reg]);
                    const float zz = sigmoidf_(giz + gz[reg]);
                    const float n  = tanhf_(gin + r * gn[reg]);
                    const size_t idx = (size_t)m * HID + j;
                    const float h  = h0f[idx];
                    const float hn = (1.f - zz) * n + zz * h;
                    h0f[idx]   = hn;
                    h0h_n[idx] = (_Float16)hn;
                }
            }
    } else {
#pragma unroll
        for (int mf = 0; mf < 2; ++mf)
#pragma unroll
            for (int jf = 0; jf < 2; ++jf)
#pragma unroll
                for (int g = 0; g < 3; ++g)
#pragma unroll
                    for (int reg = 0; reg < 4; ++reg) {
                        const int m = m0 + wm * 32 + mf * 16 + (lane >> 4) * 4 + reg;
                        const int j = j0 + wj * 32 + jf * 16 + (lane & 15);
                        gB[(size_t)m * N3H + g * HID + j] = (_Float16)acc[mf][jf][g][reg];
                    }
    }
}

// ================= L2: gi1 GEMM + fused gates1 =================
__global__ __launch_bounds__(256) void step2_kernel(
    const _Float16* __restrict__ h0h_n, const _Float16* __restrict__ wi1,
    const _Float16* __restrict__ gB,
    float* __restrict__ h1f, _Float16* __restrict__ h1h_n)
{
    const int j0 = blockIdx.x * 64;
    const int m0 = blockIdx.y * 64;

    __shared__ __align__(16) _Float16 As[64 * BK];
    __shared__ __align__(16) _Float16 Bs[192 * BK];

    const int tid  = threadIdx.x;
    const int lane = tid & 63;
    const int wid  = tid >> 6;
    const int wm   = wid >> 1, wj = wid & 1;

    floatx4 acc[2][2][3];
    const floatx4 z4 = {0.f, 0.f, 0.f, 0.f};
#pragma unroll
    for (int a = 0; a < 2; ++a)
#pragma unroll
        for (int b = 0; b < 2; ++b)
#pragma unroll
            for (int g = 0; g < 3; ++g) acc[a][b][g] = z4;

    const _Float16* a_srcp[2];
#pragma unroll
    for (int k2 = 0; k2 < 2; ++k2) {
        const int p = tid + k2 * 256, row = p >> 3, c = (p & 7) ^ (row & 7);
        a_srcp[k2] = h0h_n + (size_t)(m0 + row) * KD + c * 8;
    }
    const _Float16* b_srcp[6];
#pragma unroll
    for (int k2 = 0; k2 < 6; ++k2) {
        const int p = tid + k2 * 256, row = p >> 3, c = (p & 7) ^ (row & 7);
        const int grow = (row >> 6) * HID + j0 + (row & 63);
        b_srcp[k2] = wi1 + (size_t)grow * KD + c * 8;
    }
    _Float16* a_dst[2];
#pragma unroll
    for (int k2 = 0; k2 < 2; ++k2) a_dst[k2] = As + (size_t)(k2 * 256 + wid * 64) * 8;
    _Float16* b_dst[6];
#pragma unroll
    for (int k2 = 0; k2 < 6; ++k2) b_dst[k2] = Bs + (size_t)(k2 * 256 + wid * 64) * 8;

    const int ku = lane >> 4;
    int aoff[2][2], boff[2][3][2];
#pragma unroll
    for (int mf = 0; mf < 2; ++mf) {
        const int r = wm * 32 + mf * 16 + (lane & 15);
#pragma unroll
        for (int kk = 0; kk < 2; ++kk)
            aoff[mf][kk] = r * BK + (((kk * 4 + ku) ^ (r & 7)) * 8);
    }
#pragma unroll
    for (int jf = 0; jf < 2; ++jf)
#pragma unroll
        for (int g = 0; g < 3; ++g) {
            const int r = g * 64 + wj * 32 + jf * 16 + (lane & 15);
#pragma unroll
            for (int kk = 0; kk < 2; ++kk)
                boff[jf][g][kk] = r * BK + (((kk * 4 + ku) ^ (r & 7)) * 8);
        }

    for (int kt = 0; kt < 8; ++kt) {
        const int k0 = kt * BK;
#pragma unroll
        for (int k2 = 0; k2 < 2; ++k2) gload16(a_srcp[k2] + k0, a_dst[k2]);
#pragma unroll
        for (int k2 = 0; k2 < 6; ++k2) gload16(b_srcp[k2] + k0, b_dst[k2]);
        __syncthreads();
#pragma unroll
        for (int kk = 0; kk < 2; ++kk) {
            half8 af[2], bf[2][3];
#pragma unroll
            for (int mf = 0; mf < 2; ++mf) af[mf] = *(const half8*)(As + aoff[mf][kk]);
#pragma unroll
            for (int jf = 0; jf < 2; ++jf)
#pragma unroll
                for (int g = 0; g < 3; ++g) bf[jf][g] = *(const half8*)(Bs + boff[jf][g][kk]);
#pragma unroll
            for (int mf = 0; mf < 2; ++mf)
#pragma unroll
                for (int jf = 0; jf < 2; ++jf)
#pragma unroll
                    for (int g = 0; g < 3; ++g)
                        acc[mf][jf][g] = __builtin_amdgcn_mfma_f32_16x16x32_f16(af[mf], bf[jf][g], acc[mf][jf][g], 0, 0, 0);
        }
        __syncthreads();
    }

    // fused gates1: h1n = (1-z)*n + z*h1  (gh1 from gB)
#pragma unroll
    for (int mf = 0; mf < 2; ++mf)
#pragma unroll
        for (int jf = 0; jf < 2; ++jf) {
            const floatx4 gr = acc[mf][jf][0];
            const floatx4 gz = acc[mf][jf][1];
            const floatx4 gn = acc[mf][jf][2];
#pragma unroll
            for (int reg = 0; reg < 4; ++reg) {
                const int m = m0 + wm * 32 + mf * 16 + (lane >> 4) * 4 + reg;
                const int j = j0 + wj * 32 + jf * 16 + (lane & 15);
                const size_t gbase = (size_t)m * N3H;
                const float ghr = (float)gB[gbase + j];
                const float ghz = (float)gB[gbase + HID + j];
                const float ghn = (float)gB[gbase + 2 * HID + j];
                const float r  = sigmoidf_(gr[reg] + ghr);
                const float zz = sigmoidf_(gz[reg] + ghz);
                const float n  = tanhf_(gn[reg] + r * ghn);
                const size_t idx = (size_t)m * HID + j;
                const float h  = h1f[idx];
                const float hn = (1.f - zz) * n + zz * h;
                h1f[idx]   = hn;
                h1h_n[idx] = (_Float16)hn;
            }
        }
}

// ================= L3: heads + accumulation. One wave per batch row. =================
__global__ __launch_bounds__(256) void head_kernel(
    const _Float16* __restrict__ h1h_n,
    const float* __restrict__ Wamp, const float* __restrict__ bamp,
    const float* __restrict__ Wph,  const float* __restrict__ bph,
    const int* __restrict__ bits,
    float* __restrict__ amp, float* __restrict__ phase,
    int* __restrict__ nup, int* __restrict__ ndn,
    float* __restrict__ out, int step)
{
    const int lane = threadIdx.x & 63;
    const int m    = blockIdx.x * 4 + (threadIdx.x >> 6);
    const half8 hv = *(const half8*)(h1h_n + (size_t)m * HID + lane * 8);
    float d0 = 0.f, d1 = 0.f, d2 = 0.f, d3 = 0.f;
#pragma unroll
    for (int e = 0; e < 8; ++e) {
        const int j = lane * 8 + e;
        const float hn = (float)hv[e];
        d0 += hn * Wamp[j];       d1 += hn * Wamp[HID + j];
        d2 += hn * Wph[j];        d3 += hn * Wph[HID + j];
    }
#pragma unroll
    for (int off = 1; off < 64; off <<= 1) {
        d0 += __shfl_xor(d0, off); d1 += __shfl_xor(d1, off);
        d2 += __shfl_xor(d2, off); d3 += __shfl_xor(d3, off);
    }
    if (lane == 0) {
        const float a0 = d0 + bamp[0];
        const float a1 = d1 + bamp[1];
        const float mx = fmaxf(a0, a1);
        const float e0 = __expf(a0 - mx), e1 = __expf(a1 - mx);
        const float inv = 1.f / (e0 + e1);
        float ya0 = sqrtf(e0 * inv), ya1 = sqrtf(e1 * inv);
        const float p0 = d2 + bph[0];
        const float p1 = d3 + bph[1];
        const float yp0 = PI_F * p0 / (1.f + fabsf(p0));
        const float yp1 = PI_F * p1 / (1.f + fabsf(p1));
        const int even = ((step & 1) == 0);
        const int cnt = even ? nup[m] : ndn[m];
        if (step >= 32) {  // MIN_I
            const int lower = (step >> 1) - 16;
            const float m0v = (cnt > lower) ? ya0 : 0.f;
            const float m1v = (cnt < 16) ? ya1 : 0.f;
            const float nrm = sqrtf(m0v * m0v + m1v * m1v + 1e-12f);
            ya0 = m0v / nrm; ya1 = m1v / nrm;
        }
        const int bi = bits[m * SORB + step];
        const float na = amp[m] * (bi ? ya1 : ya0);
        const float np = phase[m] + (bi ? yp1 : yp0);
        amp[m] = na; phase[m] = np;
        if (bi) { if (even) nup[m] = cnt + 1; else ndn[m] = cnt + 1; }
        if (step == SORB - 1) {
            out[m * 2 + 0] = na;
            out[m * 2 + 1] = np;
        }
    }
}

extern "C" void kernel_launch(void* const* d_in, const int* in_sizes, int n_in,
                              void* d_out, int out_size, void* d_ws, size_t ws_size,
                              hipStream_t stream) {
    const int*   bits = (const int*)d_in[0];
    const float* Wih0 = (const float*)d_in[1];
    const float* Whh0 = (const float*)d_in[2];
    const float* Wih1 = (const float*)d_in[3];
    const float* Whh1 = (const float*)d_in[4];
    const float* Wamp = (const float*)d_in[5];
    const float* bamp = (const float*)d_in[6];
    const float* Wph  = (const float*)d_in[7];
    const float* bph  = (const float*)d_in[8];
    float* out = (float*)d_out;

    char* ws = (char*)d_ws;
    size_t off = 0;
    auto alloc = [&](size_t bytes) {
        void* p = ws + off;
        off = (off + bytes + 255) & ~(size_t)255;
        return p;
    };
    _Float16* wh0 = (_Float16*)alloc((size_t)N3H * KD * 2);
    _Float16* wi1 = (_Float16*)alloc((size_t)N3H * KD * 2);
    _Float16* wh1 = (_Float16*)alloc((size_t)N3H * KD * 2);
    float*    h0f = (float*)alloc((size_t)BATCH * HID * 4);
    float*    h1f = (float*)alloc((size_t)BATCH * HID * 4);
    _Float16* h0hA = (_Float16*)alloc((size_t)BATCH * HID * 2);
    _Float16* h0hB = (_Float16*)alloc((size_t)BATCH * HID * 2);
    _Float16* h1hA = (_Float16*)alloc((size_t)BATCH * HID * 2);
    _Float16* h1hB = (_Float16*)alloc((size_t)BATCH * HID * 2);
    _Float16* gB  = (_Float16*)alloc((size_t)BATCH * N3H * 2);
    float*    amp   = (float*)alloc((size_t)BATCH * 4);
    float*    phase = (float*)alloc((size_t)BATCH * 4);
    int*      nup   = (int*)alloc((size_t)BATCH * 4);
    int*      ndn   = (int*)alloc((size_t)BATCH * 4);

    _Float16* h0h[2] = {h0hA, h0hB};
    _Float16* h1h[2] = {h1hA, h1hB};

    hipMemsetAsync(h0f, 0, (size_t)BATCH * HID * 4, stream);
    hipMemsetAsync(h1f, 0, (size_t)BATCH * HID * 4, stream);
    hipMemsetAsync(h0hA, 0, (size_t)BATCH * HID * 2, stream);
    hipMemsetAsync(h1hA, 0, (size_t)BATCH * HID * 2, stream);
    convw_kernel<<<(N3H * KD + 255) / 256, 256, 0, stream>>>(Whh0, Wih1, Whh1, wh0, wi1, wh1);
    init_kernel<<<BATCH / 256, 256, 0, stream>>>(amp, phase, nup, ndn);

    for (int s = 0; s < SORB; ++s) {
        const int cur = s & 1, nxt = cur ^ 1;
        step1_kernel<<<dim3(8, 64, 2), 256, 0, stream>>>(
            h0h[cur], h1h[cur], wh0, wh1, Wih0, bits, h0f, h0h[nxt], gB, s);
        step2_kernel<<<dim3(8, 64, 1), 256, 0, stream>>>(
            h0h[nxt], wi1, gB, h1f, h1h[nxt]);
        head_kernel<<<BATCH / 4, 256, 0, stream>>>(
            h1h[nxt], Wamp, bamp, Wph, bph, bits, amp, phase, nup, ndn, out, s);
    }
}